// Round 19
// baseline (383.102 us; speedup 1.0000x reference)
//
#include <hip/hip_runtime.h>
#include <math.h>

#define HD    256
#define NHEAD 4
#define NSEG  1024
#define RPB   64                                    // rows per block
#define NRB64 6250                                  // 400000/64 row slabs

typedef short bf16x8 __attribute__((ext_vector_type(8)));
typedef float f32x16 __attribute__((ext_vector_type(16)));

__device__ __forceinline__ float tanh_fast(float v) {
    float e = __expf(2.0f * v);                    // overflow->inf, tanh->1: ok
    return 1.0f - 2.0f * __builtin_amdgcn_rcpf(e + 1.0f);
}

// split fp32 pair into packed bf16-hi word and bf16-lo word (truncation split;
// lo captures mantissa bits 9..17 -> per-product rel err ~2^-17). Used for W.
__device__ __forceinline__ void split2(float a, float b, unsigned &hi, unsigned &lo) {
    unsigned ba = __float_as_uint(a), bb = __float_as_uint(b);
    unsigned ha = ba & 0xFFFF0000u, hb = bb & 0xFFFF0000u;
    float la = a - __uint_as_float(ha);
    float lb = b - __uint_as_float(hb);
    hi = (ha >> 16) | hb;
    lo = (__float_as_uint(la) >> 16) | (__float_as_uint(lb) & 0xFFFF0000u);
}

// round-to-nearest bf16 pack: dst = [bf16(b) : bf16(a)] (a in low 16)
__device__ __forceinline__ unsigned cvt_pk_bf16(float a, float b) {
    unsigned r;
    asm("v_cvt_pk_bf16_f32 %0, %1, %2" : "=v"(r) : "v"(a), "v"(b));
    return r;
}

__device__ __forceinline__ void gld16(const void* g, void* l) {
    __builtin_amdgcn_global_load_lds(
        (const __attribute__((address_space(1))) void*)g,
        (__attribute__((address_space(3))) void*)l, 16, 0, 0);
}

// ---------------------------------------------------------------------------
// k0_prep: W1 (fp32 [k][c]) -> ws split-bf16 planes laid out exactly as k1's
// per-chunk LDS image, KC=16: chunk t (k in [16t,16t+16)):
//   off = t*16384 + ch*8192 + o*2048 + c*16 + j*4   (hi plane; lo at +4096)
// with o = k_local>>3, c = col within 128-col half, j = k-pair. 256 KiB total.
// ---------------------------------------------------------------------------
__global__ __launch_bounds__(256) void k0_prep(
    const float* __restrict__ W1, char* __restrict__ ws)
{
    int g = blockIdx.x * 256 + threadIdx.x;        // 32768 threads
    int c  = g & 127;
    int j  = (g >> 7) & 3;
    int o  = (g >> 9) & 1;
    int ch = (g >> 10) & 1;
    int t  = g >> 11;                              // 0..15
    int k   = t*16 + o*8 + 2*j;
    int col = ch*128 + c;
    float a = W1[(size_t)k * HD + col];
    float b = W1[(size_t)(k + 1) * HD + col];
    unsigned hw, lw;
    split2(a, b, hw, lw);
    size_t off = (size_t)t*16384 + ch*8192 + o*2048 + c*16 + j*4;
    *(unsigned*)(ws + off)        = hw;
    *(unsigned*)(ws + off + 4096) = lw;
}

// ---------------------------------------------------------------------------
// K1: partial logits for one 128-col half.
// 256 thr = 4 waves: rg=wid>>1 (2 x 32 rows), cg=wid&1 (2 x 64 cols);
// wave tile 32x64 = 2 x 32x32 mfma, acc = 32 AGPR.
// NUMERICS (R13-proven): logits ~= xh@W1h + xh@W1l, xh = rn-bf16(x).
// SYNC STRUCTURE (replay-proven): per chunk, STAGE(t+1) + x-reg prefetch
// issued FIRST, compute chunk t, __syncthreads(). No raw s_barrier.
// R19 change (T14-lite): x moves from LDS staging to PER-LANE REGISTER
// prefetch. Since __syncthreads drains vmcnt(0), the x loads issued at the
// top of iteration t are guaranteed complete right after the barrier ->
// zero-wait consumption, no new sync semantics. STAGE is W-only (drain
// volume -33%); the 2 ds_read_b128/chunk disappear. LDS staging 2x8K;
// total stays 32K (epilogue-bound) -> same 4 blocks/CU as R13/R17/R18.
// R14/R15/R16 lessons: bigger tiles halve barrier de-correlation (regress);
// 6-block occupancy thrashes L2 (regress); 1024-thr barrier-free spills
// acc to scratch (catastrophe). Keep 256-thr 4-block shape.
// ---------------------------------------------------------------------------
#define K1_THREADS 256
#define BUFB 8192
#define K1_LDS 32768

__global__ __launch_bounds__(K1_THREADS, 5) void k1_mfma(
    const float* __restrict__ x, const char* __restrict__ wsW,
    const float* __restrict__ b1, const float* __restrict__ W2,
    const float* __restrict__ b2, float* __restrict__ lgA,
    float* __restrict__ lgB, int N)
{
    extern __shared__ __align__(16) char smem[];

    const int raw = blockIdx.x;
    const int ch  = (raw >> 3) & 1;
    const int rb  = (raw >> 4) * 8 + (raw & 7);
    if (rb >= NRB64) return;

    const int tid  = threadIdx.x;
    const int lane = tid & 63;
    const int lo5  = lane & 31;
    const int hi   = lane >> 5;
    const int wid  = tid >> 6;
    const int rg   = wid >> 1;                     // 0..1 (32-row groups)
    const int cg   = wid & 1;                      // 0..1 (64-col groups)
    const int blkrow = rb * RPB;
    const int rl   = rg*32 + lo5;                  // local row this lane computes

    f32x16 acc[2];
    #pragma unroll
    for (int ct = 0; ct < 2; ++ct) {
        float b1v = b1[ch*128 + cg*64 + ct*32 + lo5];
        #pragma unroll
        for (int e = 0; e < 16; ++e) acc[ct][e] = b1v;
    }

    // W: linear from pre-split ws (2 x 16B per thread per chunk).
    const char* gwbase = wsW + ch*8192 + tid*16;   // + u*16384 per chunk
    // x: per-lane row pointer (this lane's compute row; cols t*16+hi*8..+7)
    long grow = blkrow + rl; if (grow > N-1) grow = N-1;
    const float* xr = x + grow * HD + hi*8;

    auto STAGE = [&](int u) {                      // W only (u unrolled const)
        const int db = (u & 1) * BUFB;
        const char* w = gwbase + (size_t)u*16384;
        #pragma unroll
        for (int i = 0; i < 2; ++i)
            gld16(w + i*4096, smem + db + i*4096 + tid*16);
    };

    // prologue: W chunk 0 + x chunk 0 into registers
    STAGE(0);
    float4 xq0 = *(const float4*)(xr);
    float4 xq1 = *(const float4*)(xr + 4);
    __syncthreads();                               // chunk 0 landed

    #pragma unroll
    for (int t = 0; t < 16; ++t) {
        float4 xn0, xn1;
        if (t < 15) {
            STAGE(t + 1);                          // W flies under compute
            xn0 = *(const float4*)(xr + (t+1)*16);     // x prefetch -> regs
            xn1 = *(const float4*)(xr + (t+1)*16 + 4);
        }
        const int buf = (t & 1) * BUFB;
        {
            union { unsigned u[4]; bf16x8 v; } ah;
            // A: this lane's x row from registers (ready: prev barrier
            // drained vmcnt(0)), rn-bf16 pack
            ah.u[0] = cvt_pk_bf16(xq0.x, xq0.y);
            ah.u[1] = cvt_pk_bf16(xq0.z, xq0.w);
            ah.u[2] = cvt_pk_bf16(xq1.x, xq1.y);
            ah.u[3] = cvt_pk_bf16(xq1.z, xq1.w);
            bf16x8 bh[2], bl[2];
            #pragma unroll
            for (int ct = 0; ct < 2; ++ct) {
                int off = buf + hi*2048 + (cg*64 + ct*32 + lo5)*16;
                bh[ct] = *(const bf16x8*)(smem + off);
                bl[ct] = *(const bf16x8*)(smem + off + 4096);
            }
            #pragma unroll
            for (int ct = 0; ct < 2; ++ct) {
                acc[ct] = __builtin_amdgcn_mfma_f32_32x32x16_bf16(ah.v, bh[ct], acc[ct], 0, 0, 0);
                acc[ct] = __builtin_amdgcn_mfma_f32_32x32x16_bf16(ah.v, bl[ct], acc[ct], 0, 0, 0);
            }
        }
        __syncthreads();                           // drain stage(t+1) + reuse guard
        if (t < 15) { xq0 = xn0; xq1 = xn1; }
    }

    // ---- epilogue: tanh -> h planes (split bf16, swizzled [row][col]) ------
    // hi plane [0,16K), lo plane [16K,32K). p_lds overlays [0,1K) AFTER the
    // h-plane reads complete (extra barrier) -> LDS stays 32K.
    #pragma unroll
    for (int ct = 0; ct < 2; ++ct) {
        const int col = cg*64 + ct*32 + lo5;
        #pragma unroll
        for (int e = 0; e < 16; ++e) {
            float h = tanh_fast(acc[ct][e]);
            int row = rg*32 + (e & 3) + 8*(e >> 2) + 4*hi;
            unsigned hh = __float_as_uint(h) & 0xFFFF0000u;
            float hl = h - __uint_as_float(hh);
            int byte = row*256 + ((((col >> 3) ^ (row & 15))) << 4) + (col & 7)*2;
            *(unsigned short*)(smem + byte)         = (unsigned short)(hh >> 16);
            *(unsigned short*)(smem + 16384 + byte) = (unsigned short)(__float_as_uint(hl) >> 16);
        }
    }
    __syncthreads();

    f32x16 d;
    #pragma unroll
    for (int e = 0; e < 16; ++e) d[e] = 0.0f;
    const int rt_e  = wid;                         // waves 0,1 active
    const int row_e = rt_e*32 + lo5;
    const int colh  = lo5 & 3;
    const bool act  = (wid < 2) && (lo5 < 4);
    if (wid < 2) {
        #pragma unroll
        for (int kk = 0; kk < 8; ++kk) {
            int sb = row_e*256 + (((kk*2 + hi) ^ (row_e & 15)) << 4);
            bf16x8 ahh = *(const bf16x8*)(smem + sb);
            bf16x8 alo = *(const bf16x8*)(smem + 16384 + sb);
            union { unsigned short s[8]; bf16x8 v; } wh, wl;
            #pragma unroll
            for (int j = 0; j < 8; ++j) {
                float w = W2[(size_t)(ch*128 + kk*16 + hi*8 + j)*NHEAD + colh];
                w = act ? w : 0.0f;
                unsigned hb = __float_as_uint(w) & 0xFFFF0000u;
                float wlf = w - __uint_as_float(hb);
                wh.s[j] = (unsigned short)(hb >> 16);
                wl.s[j] = (unsigned short)(__float_as_uint(wlf) >> 16);
            }
            d = __builtin_amdgcn_mfma_f32_32x32x16_bf16(ahh, wh.v, d, 0, 0, 0);
            d = __builtin_amdgcn_mfma_f32_32x32x16_bf16(ahh, wl.v, d, 0, 0, 0);
            d = __builtin_amdgcn_mfma_f32_32x32x16_bf16(alo, wh.v, d, 0, 0, 0);
        }
    }
    __syncthreads();                               // all h-plane reads done

    float* p_lds = (float*)smem;                   // [64][4] overlays h-hi
    if (act) {                                     // D scatter by C-layout
        #pragma unroll
        for (int e = 0; e < 16; ++e) {
            int r = rt_e*32 + (e & 3) + 8*(e >> 2) + 4*hi;
            p_lds[r*4 + lo5] = d[e];
        }
    }
    __syncthreads();
    if (tid < RPB) {
        int g2 = blkrow + tid;
        if (g2 < N) {
            float4 o = *(float4*)(p_lds + tid*4);
            float* dst;
            if (ch == 0) {
                o.x += b2[0]; o.y += b2[1]; o.z += b2[2]; o.w += b2[3];
                dst = lgA;
            } else dst = lgB;
            *(float4*)(dst + (size_t)g2 * NHEAD) = o;
        }
    }
}

// ---------------------------------------------------------------------------
__device__ __forceinline__ int lower_bound(const int* __restrict__ a, int n, int v) {
    int lo = 0, hi = n;
    while (lo < hi) { int m = (lo + hi) >> 1; if (a[m] < v) lo = m + 1; else hi = m; }
    return lo;
}

// ---------------------------------------------------------------------------
// K23: FUSED k2+k3 (R18-verified, verbatim). Phase A: per-segment max &
// sum-of-exp of (lgA+lgB), stats in registers. Phase B: attn = e/(sum+eps)
// written over lgA; z = sum attn*x; graph_emb = z@Wt + (sum attn)*bt.
// ---------------------------------------------------------------------------
__global__ __launch_bounds__(256) void k23_seg_pool(
    const int* __restrict__ batch, const float* __restrict__ x,
    const float* __restrict__ Wt, const float* __restrict__ bt,
    const float* __restrict__ lgB, float* __restrict__ out, int N)
{
    const int b = blockIdx.x;
    const int tid = threadIdx.x;
    const int lane = tid & 63, wid = tid >> 6;
    const int start = lower_bound(batch, N, b);
    const int end   = lower_bound(batch, N, b + 1);

    float4* at4 = (float4*)(out + (size_t)NSEG * HD);   // lgA: logits -> attn
    const float4* lb4 = (const float4*)lgB;

    // ---- Phase A: segment max ----
    float4 mx = make_float4(-INFINITY, -INFINITY, -INFINITY, -INFINITY);
    for (int i = start + tid; i < end; i += 256) {
        float4 a = at4[i], bq = lb4[i];
        mx.x = fmaxf(mx.x, a.x + bq.x); mx.y = fmaxf(mx.y, a.y + bq.y);
        mx.z = fmaxf(mx.z, a.z + bq.z); mx.w = fmaxf(mx.w, a.w + bq.w);
    }
    #pragma unroll
    for (int ofs = 32; ofs >= 1; ofs >>= 1) {
        mx.x = fmaxf(mx.x, __shfl_xor(mx.x, ofs, 64));
        mx.y = fmaxf(mx.y, __shfl_xor(mx.y, ofs, 64));
        mx.z = fmaxf(mx.z, __shfl_xor(mx.z, ofs, 64));
        mx.w = fmaxf(mx.w, __shfl_xor(mx.w, ofs, 64));
    }
    __shared__ float4 red[4];
    if (lane == 0) red[wid] = mx;
    __syncthreads();
    float4 smax;
    smax.x = fmaxf(fmaxf(red[0].x, red[1].x), fmaxf(red[2].x, red[3].x));
    smax.y = fmaxf(fmaxf(red[0].y, red[1].y), fmaxf(red[2].y, red[3].y));
    smax.z = fmaxf(fmaxf(red[0].z, red[1].z), fmaxf(red[2].z, red[3].z));
    smax.w = fmaxf(fmaxf(red[0].w, red[1].w), fmaxf(red[2].w, red[3].w));
    __syncthreads();

    // ---- Phase A: segment sum of exp ----
    float4 sm = make_float4(0.f, 0.f, 0.f, 0.f);
    for (int i = start + tid; i < end; i += 256) {
        float4 a = at4[i], bq = lb4[i];
        sm.x += __expf(a.x + bq.x - smax.x); sm.y += __expf(a.y + bq.y - smax.y);
        sm.z += __expf(a.z + bq.z - smax.z); sm.w += __expf(a.w + bq.w - smax.w);
    }
    #pragma unroll
    for (int ofs = 32; ofs >= 1; ofs >>= 1) {
        sm.x += __shfl_xor(sm.x, ofs, 64);
        sm.y += __shfl_xor(sm.y, ofs, 64);
        sm.z += __shfl_xor(sm.z, ofs, 64);
        sm.w += __shfl_xor(sm.w, ofs, 64);
    }
    if (lane == 0) red[wid] = sm;
    __syncthreads();
    float4 ssum;                                   // all threads
    ssum.x = red[0].x + red[1].x + red[2].x + red[3].x;
    ssum.y = red[0].y + red[1].y + red[2].y + red[3].y;
    ssum.z = red[0].z + red[1].z + red[2].z + red[3].z;
    ssum.w = red[0].w + red[1].w + red[2].w + red[3].w;
    __syncthreads();                               // red reads done (attn_s next)

    // ---- Phase B: attn write + z accumulation + z@Wt ----
    float4 inv;
    inv.x = 1.0f / (ssum.x + 1e-16f); inv.y = 1.0f / (ssum.y + 1e-16f);
    inv.z = 1.0f / (ssum.z + 1e-16f); inv.w = 1.0f / (ssum.w + 1e-16f);

    float z0 = 0.f, z1 = 0.f, z2 = 0.f, z3 = 0.f;
    __shared__ float4 attn_s[256];

    for (int c0 = start; c0 < end; c0 += 256) {
        const int idx = c0 + tid;
        if (idx < end) {
            float4 l  = at4[idx];
            float4 lb = lb4[idx];
            float4 a;
            a.x = __expf(l.x + lb.x - smax.x) * inv.x;
            a.y = __expf(l.y + lb.y - smax.y) * inv.y;
            a.z = __expf(l.z + lb.z - smax.z) * inv.z;
            a.w = __expf(l.w + lb.w - smax.w) * inv.w;
            at4[idx] = a;          // final attn output
            attn_s[tid] = a;
        }
        __syncthreads();
        const int cnt = min(256, end - c0);
        const float* xb = x + (size_t)c0 * HD + tid;
        #pragma unroll 4
        for (int i = 0; i < cnt; ++i) {
            float4 a = attn_s[i];
            float xv = xb[(size_t)i * HD];
            z0 = fmaf(a.x, xv, z0); z1 = fmaf(a.y, xv, z1);
            z2 = fmaf(a.z, xv, z2); z3 = fmaf(a.w, xv, z3);
        }
        __syncthreads();
    }

    __shared__ float zs[NHEAD][HD];
    zs[0][tid] = z0; zs[1][tid] = z1; zs[2][tid] = z2; zs[3][tid] = z3;
    __syncthreads();

    const int h = tid >> 6;                      // wave-uniform
    float smh, invh;
    if      (h == 0) { smh = ssum.x; invh = inv.x; }
    else if (h == 1) { smh = ssum.y; invh = inv.y; }
    else if (h == 2) { smh = ssum.z; invh = inv.z; }
    else             { smh = ssum.w; invh = inv.w; }

    float acc = smh * invh * bt[tid];            // (sum attn_h) * bt[j]
    #pragma unroll 4
    for (int k = 0; k < HD; ++k)
        acc = fmaf(zs[h][k], Wt[(size_t)k * HD + tid], acc);

    out[(size_t)b * HD + tid] = acc;             // single write, no stash
}

// ---------------------------------------------------------------------------
extern "C" void kernel_launch(void* const* d_in, const int* in_sizes, int n_in,
                              void* d_out, int out_size, void* d_ws, size_t ws_size,
                              hipStream_t stream) {
    const float* x   = (const float*)d_in[0];
    const int*   bat = (const int*)  d_in[1];
    const float* W1  = (const float*)d_in[2];
    const float* b1  = (const float*)d_in[3];
    const float* W2  = (const float*)d_in[4];
    const float* b2  = (const float*)d_in[5];
    const float* Wt  = (const float*)d_in[6];
    const float* bt  = (const float*)d_in[7];
    float* out = (float*)d_out;
    const int N = in_sizes[0] / HD;

    float* lgA = out + (size_t)NSEG * HD;          // attn region of d_out
    char*  wsW = (char*)d_ws;                      // [0,256K): split W planes
    float* lgB = (float*)((char*)d_ws + 262144);   // [256K,+6.4M): partial logits

    hipLaunchKernelGGL(k0_prep, dim3(128), dim3(256), 0, stream, W1, wsW);
    hipLaunchKernelGGL(k1_mfma, dim3(((NRB64 + 7) / 8) * 16), dim3(K1_THREADS),
                       K1_LDS, stream, x, wsW, b1, W2, b2, lgA, lgB, N);
    hipLaunchKernelGGL(k23_seg_pool, dim3(NSEG), dim3(256), 0, stream,
                       bat, x, Wt, bt, lgB, out, N);
}

// Round 20
// 328.484 us; speedup vs baseline: 1.1663x; 1.1663x over previous
//
#include <hip/hip_runtime.h>
#include <math.h>

#define HD    256
#define NHEAD 4
#define NSEG  1024
#define RPB   64                                    // rows per block
#define NRB64 6250                                  // 400000/64 row slabs

typedef short bf16x8 __attribute__((ext_vector_type(8)));
typedef float f32x16 __attribute__((ext_vector_type(16)));

__device__ __forceinline__ float tanh_fast(float v) {
    float e = __expf(2.0f * v);                    // overflow->inf, tanh->1: ok
    return 1.0f - 2.0f * __builtin_amdgcn_rcpf(e + 1.0f);
}

// split fp32 pair into packed bf16-hi word and bf16-lo word (truncation split;
// lo captures mantissa bits 9..17 -> per-product rel err ~2^-17). Used for W.
__device__ __forceinline__ void split2(float a, float b, unsigned &hi, unsigned &lo) {
    unsigned ba = __float_as_uint(a), bb = __float_as_uint(b);
    unsigned ha = ba & 0xFFFF0000u, hb = bb & 0xFFFF0000u;
    float la = a - __uint_as_float(ha);
    float lb = b - __uint_as_float(hb);
    hi = (ha >> 16) | hb;
    lo = (__float_as_uint(la) >> 16) | (__float_as_uint(lb) & 0xFFFF0000u);
}

// round-to-nearest bf16 pack: dst = [bf16(b) : bf16(a)] (a in low 16)
__device__ __forceinline__ unsigned cvt_pk_bf16(float a, float b) {
    unsigned r;
    asm("v_cvt_pk_bf16_f32 %0, %1, %2" : "=v"(r) : "v"(a), "v"(b));
    return r;
}

__device__ __forceinline__ void gld16(const void* g, void* l) {
    __builtin_amdgcn_global_load_lds(
        (const __attribute__((address_space(1))) void*)g,
        (__attribute__((address_space(3))) void*)l, 16, 0, 0);
}

// ---------------------------------------------------------------------------
// k0_prep: W1 (fp32 [k][c]) -> ws split-bf16 planes laid out exactly as k1's
// per-chunk LDS image, KC=16: chunk t (k in [16t,16t+16)):
//   off = t*16384 + ch*8192 + o*2048 + c*16 + j*4   (hi plane; lo at +4096)
// with o = k_local>>3, c = col within 128-col half, j = k-pair. 256 KiB total.
// ---------------------------------------------------------------------------
__global__ __launch_bounds__(256) void k0_prep(
    const float* __restrict__ W1, char* __restrict__ ws)
{
    int g = blockIdx.x * 256 + threadIdx.x;        // 32768 threads
    int c  = g & 127;
    int j  = (g >> 7) & 3;
    int o  = (g >> 9) & 1;
    int ch = (g >> 10) & 1;
    int t  = g >> 11;                              // 0..15
    int k   = t*16 + o*8 + 2*j;
    int col = ch*128 + c;
    float a = W1[(size_t)k * HD + col];
    float b = W1[(size_t)(k + 1) * HD + col];
    unsigned hw, lw;
    split2(a, b, hw, lw);
    size_t off = (size_t)t*16384 + ch*8192 + o*2048 + c*16 + j*4;
    *(unsigned*)(ws + off)        = hw;
    *(unsigned*)(ws + off + 4096) = lw;
}

// ---------------------------------------------------------------------------
// K1: partial logits for one 128-col half. (R13/R17/R18-verified, verbatim.)
// 256 thr = 4 waves: rg=wid>>1 (2 x 32 rows), cg=wid&1 (2 x 64 cols);
// wave tile 32x64 = 2 x 32x32 mfma, acc = 32 AGPR.
// NUMERICS (2-term): logits ~= xh@W1h + xh@W1l, xh = rn-bf16(x) via
// v_cvt_pk_bf16_f32; W1 stays hi+lo (2^-17). Error ~1e-3; threshold 7e-3.
// SYNC STRUCTURE (replay-proven): per chunk, STAGE(t+1) first (loads fly
// under compute), compute chunk t, __syncthreads(). No raw s_barrier.
// KC=16: buffer [W 8K][x 4K] x2 = 24K staging; epilogue 32K -> 4 blocks/CU.
// Session lessons: R10 counted-vmcnt raw-barrier raced under replay; R14
// bigger tiles halve barrier de-correlation; R15 6-block occupancy thrashes
// L2 (FETCH +73%); R16 1024-thr barrier-free spills acc to scratch; R19
// per-lane x-reg prefetch scatters VMEM requests (k1 +21%). gld16's
// wave-wide 1KB bursts are the minimum-request encoding of x staging.
// This config is the verified optimum of the explored space.
// ---------------------------------------------------------------------------
#define K1_THREADS 256
#define BUFB 12288
#define K1_LDS 32768

__global__ __launch_bounds__(K1_THREADS, 5) void k1_mfma(
    const float* __restrict__ x, const char* __restrict__ wsW,
    const float* __restrict__ b1, const float* __restrict__ W2,
    const float* __restrict__ b2, float* __restrict__ lgA,
    float* __restrict__ lgB, int N)
{
    extern __shared__ __align__(16) char smem[];

    const int raw = blockIdx.x;
    const int ch  = (raw >> 3) & 1;
    const int rb  = (raw >> 4) * 8 + (raw & 7);
    if (rb >= NRB64) return;

    const int tid  = threadIdx.x;
    const int lane = tid & 63;
    const int lo5  = lane & 31;
    const int hi   = lane >> 5;
    const int wid  = tid >> 6;
    const int rg   = wid >> 1;                     // 0..1 (32-row groups)
    const int cg   = wid & 1;                      // 0..1 (64-col groups)
    const int blkrow = rb * RPB;
    const int rl   = rg*32 + lo5;                  // local row this lane computes

    f32x16 acc[2];
    #pragma unroll
    for (int ct = 0; ct < 2; ++ct) {
        float b1v = b1[ch*128 + cg*64 + ct*32 + lo5];
        #pragma unroll
        for (int e = 0; e < 16; ++e) acc[ct][e] = b1v;
    }

    // stage sources. W: linear from pre-split ws (2 x 16B per thread).
    // x: row-major [row][slot] image, slot pre-swizzled (slot ^ row&3).
    const char* gwbase = wsW + ch*8192 + tid*16;   // + u*16384 per chunk
    const char* gxbase;
    {
        int row  = tid >> 2;                       // 0..63
        int slot = tid & 3;
        long grow = blkrow + row; if (grow > N-1) grow = N-1;
        gxbase = (const char*)x + grow*1024 + ((slot ^ (row & 3)) * 16);
    }

    auto STAGE = [&](int u) {                      // u uniform (unrolled const)
        const int db = (u & 1) * BUFB;
        const char* w = gwbase + (size_t)u*16384;
        #pragma unroll
        for (int i = 0; i < 2; ++i)
            gld16(w + i*4096, smem + db + i*4096 + tid*16);
        gld16(gxbase + (size_t)u*64, smem + db + 8192 + tid*16);
    };

    STAGE(0);
    __syncthreads();                               // chunk 0 landed

    #pragma unroll
    for (int t = 0; t < 16; ++t) {
        if (t < 15) STAGE(t + 1);                  // fly under compute
        const int buf = (t & 1) * BUFB;
        {
            union { unsigned u[4]; bf16x8 v; } ah;
            {   // A: x fp32 rows from LDS, read-side slot XOR, rn-bf16 pack
                const int s0 = hi*2;
                const int xb = buf + 8192 + rl*64;
                float4 q0 = *(const float4*)(smem + xb + ((s0     ^ (rl & 3)) << 4));
                float4 q1 = *(const float4*)(smem + xb + (((s0+1) ^ (rl & 3)) << 4));
                ah.u[0] = cvt_pk_bf16(q0.x, q0.y);
                ah.u[1] = cvt_pk_bf16(q0.z, q0.w);
                ah.u[2] = cvt_pk_bf16(q1.x, q1.y);
                ah.u[3] = cvt_pk_bf16(q1.z, q1.w);
            }
            bf16x8 bh[2], bl[2];
            #pragma unroll
            for (int ct = 0; ct < 2; ++ct) {
                int off = buf + hi*2048 + (cg*64 + ct*32 + lo5)*16;
                bh[ct] = *(const bf16x8*)(smem + off);
                bl[ct] = *(const bf16x8*)(smem + off + 4096);
            }
            #pragma unroll
            for (int ct = 0; ct < 2; ++ct) {
                acc[ct] = __builtin_amdgcn_mfma_f32_32x32x16_bf16(ah.v, bh[ct], acc[ct], 0, 0, 0);
                acc[ct] = __builtin_amdgcn_mfma_f32_32x32x16_bf16(ah.v, bl[ct], acc[ct], 0, 0, 0);
            }
        }
        __syncthreads();                           // drain stage(t+1) + reuse guard
    }

    // ---- epilogue: tanh -> h planes (split bf16, swizzled [row][col]) ------
    // hi plane [0,16K), lo plane [16K,32K). p_lds overlays [0,1K) AFTER the
    // h-plane reads complete (extra barrier) -> LDS stays 32K.
    #pragma unroll
    for (int ct = 0; ct < 2; ++ct) {
        const int col = cg*64 + ct*32 + lo5;
        #pragma unroll
        for (int e = 0; e < 16; ++e) {
            float h = tanh_fast(acc[ct][e]);
            int row = rg*32 + (e & 3) + 8*(e >> 2) + 4*hi;
            unsigned hh = __float_as_uint(h) & 0xFFFF0000u;
            float hl = h - __uint_as_float(hh);
            int byte = row*256 + ((((col >> 3) ^ (row & 15))) << 4) + (col & 7)*2;
            *(unsigned short*)(smem + byte)         = (unsigned short)(hh >> 16);
            *(unsigned short*)(smem + 16384 + byte) = (unsigned short)(__float_as_uint(hl) >> 16);
        }
    }
    __syncthreads();

    f32x16 d;
    #pragma unroll
    for (int e = 0; e < 16; ++e) d[e] = 0.0f;
    const int rt_e  = wid;                         // waves 0,1 active
    const int row_e = rt_e*32 + lo5;
    const int colh  = lo5 & 3;
    const bool act  = (wid < 2) && (lo5 < 4);
    if (wid < 2) {
        #pragma unroll
        for (int kk = 0; kk < 8; ++kk) {
            int sb = row_e*256 + (((kk*2 + hi) ^ (row_e & 15)) << 4);
            bf16x8 ahh = *(const bf16x8*)(smem + sb);
            bf16x8 alo = *(const bf16x8*)(smem + 16384 + sb);
            union { unsigned short s[8]; bf16x8 v; } wh, wl;
            #pragma unroll
            for (int j = 0; j < 8; ++j) {
                float w = W2[(size_t)(ch*128 + kk*16 + hi*8 + j)*NHEAD + colh];
                w = act ? w : 0.0f;
                unsigned hb = __float_as_uint(w) & 0xFFFF0000u;
                float wlf = w - __uint_as_float(hb);
                wh.s[j] = (unsigned short)(hb >> 16);
                wl.s[j] = (unsigned short)(__float_as_uint(wlf) >> 16);
            }
            d = __builtin_amdgcn_mfma_f32_32x32x16_bf16(ahh, wh.v, d, 0, 0, 0);
            d = __builtin_amdgcn_mfma_f32_32x32x16_bf16(ahh, wl.v, d, 0, 0, 0);
            d = __builtin_amdgcn_mfma_f32_32x32x16_bf16(alo, wh.v, d, 0, 0, 0);
        }
    }
    __syncthreads();                               // all h-plane reads done

    float* p_lds = (float*)smem;                   // [64][4] overlays h-hi
    if (act) {                                     // D scatter by C-layout
        #pragma unroll
        for (int e = 0; e < 16; ++e) {
            int r = rt_e*32 + (e & 3) + 8*(e >> 2) + 4*hi;
            p_lds[r*4 + lo5] = d[e];
        }
    }
    __syncthreads();
    if (tid < RPB) {
        int grow = blkrow + tid;
        if (grow < N) {
            float4 o = *(float4*)(p_lds + tid*4);
            float* dst;
            if (ch == 0) {
                o.x += b2[0]; o.y += b2[1]; o.z += b2[2]; o.w += b2[3];
                dst = lgA;
            } else dst = lgB;
            *(float4*)(dst + (size_t)grow * NHEAD) = o;
        }
    }
}

// ---------------------------------------------------------------------------
__device__ __forceinline__ int lower_bound(const int* __restrict__ a, int n, int v) {
    int lo = 0, hi = n;
    while (lo < hi) { int m = (lo + hi) >> 1; if (a[m] < v) lo = m + 1; else hi = m; }
    return lo;
}

// ---------------------------------------------------------------------------
// K23: FUSED k2+k3 (R18-verified, verbatim). Phase A: per-segment max &
// sum-of-exp of (lgA+lgB), stats in registers. Phase B: attn = e/(sum+eps)
// written over lgA; z = sum attn*x; graph_emb = z@Wt + (sum attn)*bt.
// ---------------------------------------------------------------------------
__global__ __launch_bounds__(256) void k23_seg_pool(
    const int* __restrict__ batch, const float* __restrict__ x,
    const float* __restrict__ Wt, const float* __restrict__ bt,
    const float* __restrict__ lgB, float* __restrict__ out, int N)
{
    const int b = blockIdx.x;
    const int tid = threadIdx.x;
    const int lane = tid & 63, wid = tid >> 6;
    const int start = lower_bound(batch, N, b);
    const int end   = lower_bound(batch, N, b + 1);

    float4* at4 = (float4*)(out + (size_t)NSEG * HD);   // lgA: logits -> attn
    const float4* lb4 = (const float4*)lgB;

    // ---- Phase A: segment max ----
    float4 mx = make_float4(-INFINITY, -INFINITY, -INFINITY, -INFINITY);
    for (int i = start + tid; i < end; i += 256) {
        float4 a = at4[i], bq = lb4[i];
        mx.x = fmaxf(mx.x, a.x + bq.x); mx.y = fmaxf(mx.y, a.y + bq.y);
        mx.z = fmaxf(mx.z, a.z + bq.z); mx.w = fmaxf(mx.w, a.w + bq.w);
    }
    #pragma unroll
    for (int ofs = 32; ofs >= 1; ofs >>= 1) {
        mx.x = fmaxf(mx.x, __shfl_xor(mx.x, ofs, 64));
        mx.y = fmaxf(mx.y, __shfl_xor(mx.y, ofs, 64));
        mx.z = fmaxf(mx.z, __shfl_xor(mx.z, ofs, 64));
        mx.w = fmaxf(mx.w, __shfl_xor(mx.w, ofs, 64));
    }
    __shared__ float4 red[4];
    if (lane == 0) red[wid] = mx;
    __syncthreads();
    float4 smax;
    smax.x = fmaxf(fmaxf(red[0].x, red[1].x), fmaxf(red[2].x, red[3].x));
    smax.y = fmaxf(fmaxf(red[0].y, red[1].y), fmaxf(red[2].y, red[3].y));
    smax.z = fmaxf(fmaxf(red[0].z, red[1].z), fmaxf(red[2].z, red[3].z));
    smax.w = fmaxf(fmaxf(red[0].w, red[1].w), fmaxf(red[2].w, red[3].w));
    __syncthreads();

    // ---- Phase A: segment sum of exp ----
    float4 sm = make_float4(0.f, 0.f, 0.f, 0.f);
    for (int i = start + tid; i < end; i += 256) {
        float4 a = at4[i], bq = lb4[i];
        sm.x += __expf(a.x + bq.x - smax.x); sm.y += __expf(a.y + bq.y - smax.y);
        sm.z += __expf(a.z + bq.z - smax.z); sm.w += __expf(a.w + bq.w - smax.w);
    }
    #pragma unroll
    for (int ofs = 32; ofs >= 1; ofs >>= 1) {
        sm.x += __shfl_xor(sm.x, ofs, 64);
        sm.y += __shfl_xor(sm.y, ofs, 64);
        sm.z += __shfl_xor(sm.z, ofs, 64);
        sm.w += __shfl_xor(sm.w, ofs, 64);
    }
    if (lane == 0) red[wid] = sm;
    __syncthreads();
    float4 ssum;                                   // all threads
    ssum.x = red[0].x + red[1].x + red[2].x + red[3].x;
    ssum.y = red[0].y + red[1].y + red[2].y + red[3].y;
    ssum.z = red[0].z + red[1].z + red[2].z + red[3].z;
    ssum.w = red[0].w + red[1].w + red[2].w + red[3].w;
    __syncthreads();                               // red reads done (attn_s next)

    // ---- Phase B: attn write + z accumulation + z@Wt ----
    float4 inv;
    inv.x = 1.0f / (ssum.x + 1e-16f); inv.y = 1.0f / (ssum.y + 1e-16f);
    inv.z = 1.0f / (ssum.z + 1e-16f); inv.w = 1.0f / (ssum.w + 1e-16f);

    float z0 = 0.f, z1 = 0.f, z2 = 0.f, z3 = 0.f;
    __shared__ float4 attn_s[256];

    for (int c0 = start; c0 < end; c0 += 256) {
        const int idx = c0 + tid;
        if (idx < end) {
            float4 l  = at4[idx];
            float4 lb = lb4[idx];
            float4 a;
            a.x = __expf(l.x + lb.x - smax.x) * inv.x;
            a.y = __expf(l.y + lb.y - smax.y) * inv.y;
            a.z = __expf(l.z + lb.z - smax.z) * inv.z;
            a.w = __expf(l.w + lb.w - smax.w) * inv.w;
            at4[idx] = a;          // final attn output
            attn_s[tid] = a;
        }
        __syncthreads();
        const int cnt = min(256, end - c0);
        const float* xb = x + (size_t)c0 * HD + tid;
        #pragma unroll 4
        for (int i = 0; i < cnt; ++i) {
            float4 a = attn_s[i];
            float xv = xb[(size_t)i * HD];
            z0 = fmaf(a.x, xv, z0); z1 = fmaf(a.y, xv, z1);
            z2 = fmaf(a.z, xv, z2); z3 = fmaf(a.w, xv, z3);
        }
        __syncthreads();
    }

    __shared__ float zs[NHEAD][HD];
    zs[0][tid] = z0; zs[1][tid] = z1; zs[2][tid] = z2; zs[3][tid] = z3;
    __syncthreads();

    const int h = tid >> 6;                      // wave-uniform
    float smh, invh;
    if      (h == 0) { smh = ssum.x; invh = inv.x; }
    else if (h == 1) { smh = ssum.y; invh = inv.y; }
    else if (h == 2) { smh = ssum.z; invh = inv.z; }
    else             { smh = ssum.w; invh = inv.w; }

    float acc = smh * invh * bt[tid];            // (sum attn_h) * bt[j]
    #pragma unroll 4
    for (int k = 0; k < HD; ++k)
        acc = fmaf(zs[h][k], Wt[(size_t)k * HD + tid], acc);

    out[(size_t)b * HD + tid] = acc;             // single write, no stash
}

// ---------------------------------------------------------------------------
extern "C" void kernel_launch(void* const* d_in, const int* in_sizes, int n_in,
                              void* d_out, int out_size, void* d_ws, size_t ws_size,
                              hipStream_t stream) {
    const float* x   = (const float*)d_in[0];
    const int*   bat = (const int*)  d_in[1];
    const float* W1  = (const float*)d_in[2];
    const float* b1  = (const float*)d_in[3];
    const float* W2  = (const float*)d_in[4];
    const float* b2  = (const float*)d_in[5];
    const float* Wt  = (const float*)d_in[6];
    const float* bt  = (const float*)d_in[7];
    float* out = (float*)d_out;
    const int N = in_sizes[0] / HD;

    float* lgA = out + (size_t)NSEG * HD;          // attn region of d_out
    char*  wsW = (char*)d_ws;                      // [0,256K): split W planes
    float* lgB = (float*)((char*)d_ws + 262144);   // [256K,+6.4M): partial logits

    hipLaunchKernelGGL(k0_prep, dim3(128), dim3(256), 0, stream, W1, wsW);
    hipLaunchKernelGGL(k1_mfma, dim3(((NRB64 + 7) / 8) * 16), dim3(K1_THREADS),
                       K1_LDS, stream, x, wsW, b1, W2, b2, lgA, lgB, N);
    hipLaunchKernelGGL(k23_seg_pool, dim3(NSEG), dim3(256), 0, stream,
                       bat, x, Wt, bt, lgB, out, N);
}